// Round 1
// baseline (341.006 us; speedup 1.0000x reference)
//
#include <hip/hip_runtime.h>

// DisplaceChannel: B=32, C=384 (48 pos x 8 ch), H=W=64, K=3, SIGMA=0.5.
// out(y,x) = sum_dy gy[dy] * sum_dx gx[dx] * mask * inp(y+dy-oy, x+dx-ox)
// Gaussian kernel is separable; displacement mask and conv zero-pad mask are
// separable per-dimension and uniform per plane (block).

constexpr int HH = 64;
constexpr int WW = 64;
constexpr int B_ = 32;
constexpr int C_ = 384;
constexpr int PLANES = B_ * C_;  // 12288

__global__ __launch_bounds__(256) void displace_conv_kernel(
    const float* __restrict__ inp, const float* __restrict__ offset,
    float* __restrict__ out) {
  const int plane = blockIdx.x;          // [0, 12288)
  const int c = plane % C_;
  const int pos = c >> 3;                // 8 channels per position

  const float offx = offset[2 * pos + 0];
  const float offy = offset[2 * pos + 1];
  const float rx = rintf(offx);          // matches jnp.round (half-even)
  const float ry = rintf(offy);
  const int ox = (int)rx;
  const int oy = (int)ry;
  const float fx = offx - rx;
  const float fy = offy - ry;

  // Separable Gaussian taps, normalized by full 3x3 sum = Sx*Sy.
  float gx0 = __expf(-2.f * (fx - 1.f) * (fx - 1.f));
  float gx1 = __expf(-2.f * fx * fx);
  float gx2 = __expf(-2.f * (fx + 1.f) * (fx + 1.f));
  const float sxi = 1.f / (gx0 + gx1 + gx2);
  gx0 *= sxi; gx1 *= sxi; gx2 *= sxi;

  float gy0 = __expf(-2.f * (fy - 1.f) * (fy - 1.f));
  float gy1 = __expf(-2.f * fy * fy);
  float gy2 = __expf(-2.f * (fy + 1.f) * (fy + 1.f));
  const float syi = 1.f / (gy0 + gy1 + gy2);
  gy0 *= syi; gy1 *= syi; gy2 *= syi;

  const int t = threadIdx.x;
  const int x = t & 63;                  // lane-consecutive column -> coalesced
  const int y0 = (t >> 6) << 4;          // 4 row-groups of 16 rows

  // Valid source window: col tap x+dx must satisfy 0<=x+dx<64 (conv pad) and
  // 0<=x+dx-ox<64 (displacement) -> x+dx in [xlo, xhi). Same for rows.
  const int xlo = ox > 0 ? ox : 0;
  const int xhi = ox < 0 ? 64 + ox : 64;
  const int ylo = oy > 0 ? oy : 0;
  const int yhi = oy < 0 ? 64 + oy : 64;

  // Fold per-lane column masks into the tap weights; load from clamped addrs.
  const float wx0 = (x - 1 >= xlo && x - 1 < xhi) ? gx0 : 0.f;
  const float wx1 = (x     >= xlo && x     < xhi) ? gx1 : 0.f;
  const float wx2 = (x + 1 >= xlo && x + 1 < xhi) ? gx2 : 0.f;

  const int c0 = min(63, max(0, x - 1 - ox));
  const int c1 = min(63, max(0, x     - ox));
  const int c2 = min(63, max(0, x + 1 - ox));

  const float* __restrict__ base = inp + (size_t)plane * (HH * WW);
  float* __restrict__ obase = out + (size_t)plane * (HH * WW);

  // Horizontal pass for one row y' (wave-uniform branch: yy uniform per wave).
  auto tmprow = [&](int yy) -> float {
    if (yy < ylo || yy >= yhi) return 0.f;   // covers conv pad + displacement
    const float* r = base + (yy - oy) * WW;
    return wx0 * r[c0] + wx1 * r[c1] + wx2 * r[c2];
  };

  // Vertical 3-tap sliding window in registers.
  float t0 = tmprow(y0 - 1);
  float t1 = tmprow(y0);
#pragma unroll
  for (int i = 0; i < 16; ++i) {
    const int y = y0 + i;
    const float t2 = tmprow(y + 1);
    obase[y * WW + x] = gy0 * t0 + gy1 * t1 + gy2 * t2;
    t0 = t1;
    t1 = t2;
  }
}

extern "C" void kernel_launch(void* const* d_in, const int* in_sizes, int n_in,
                              void* d_out, int out_size, void* d_ws, size_t ws_size,
                              hipStream_t stream) {
  const float* inp = (const float*)d_in[0];
  const float* offset = (const float*)d_in[1];
  float* out = (float*)d_out;
  displace_conv_kernel<<<PLANES, 256, 0, stream>>>(inp, offset, out);
}

// Round 2
// 319.599 us; speedup vs baseline: 1.0670x; 1.0670x over previous
//
#include <hip/hip_runtime.h>

// DisplaceChannel: B=32, C=384 (48 pos x 8 ch), H=W=64, K=3, SIGMA=0.5.
// out(y,x) = sum_dy gy[dy] * sum_dx gx[dx] * mask * inp(y+dy-oy, x+dx-ox)
// Separable Gaussian; displacement mask and conv zero-pad mask are separable
// per-dimension and uniform per plane (block). v2: 4x4 outputs per thread,
// 16B/lane vector loads+stores (VMEM instr count 70 -> 16 per thread).

constexpr int HH = 64;
constexpr int WW = 64;
constexpr int B_ = 32;
constexpr int C_ = 384;
constexpr int PLANES = B_ * C_;                    // 12288
constexpr long long NELEM = (long long)PLANES * HH * WW;

__global__ __launch_bounds__(256) void displace_conv_v2(
    const float* __restrict__ inp, const float* __restrict__ offset,
    float* __restrict__ out) {
  const int plane = blockIdx.x;                    // [0, 12288)
  const int c = plane % C_;
  const int pos = c >> 3;                          // 8 channels per position

  const float offx = offset[2 * pos + 0];
  const float offy = offset[2 * pos + 1];
  const float rx = rintf(offx);                    // matches jnp.round
  const float ry = rintf(offy);
  const int ox = (int)rx;
  const int oy = (int)ry;
  const float fx = offx - rx;
  const float fy = offy - ry;

  // Separable Gaussian taps, normalized so (sum gx)*(sum gy) = full 3x3 sum.
  float gx0 = __expf(-2.f * (fx - 1.f) * (fx - 1.f));
  float gx1 = __expf(-2.f * fx * fx);
  float gx2 = __expf(-2.f * (fx + 1.f) * (fx + 1.f));
  const float sxi = 1.f / (gx0 + gx1 + gx2);
  gx0 *= sxi; gx1 *= sxi; gx2 *= sxi;

  float gy0 = __expf(-2.f * (fy - 1.f) * (fy - 1.f));
  float gy1 = __expf(-2.f * fy * fy);
  float gy2 = __expf(-2.f * (fy + 1.f) * (fy + 1.f));
  const float syi = 1.f / (gy0 + gy1 + gy2);
  gy0 *= syi; gy1 *= syi; gy2 *= syi;

  const int t = threadIdx.x;
  const int cg = t & 15;                           // column group: cols 4cg..4cg+3
  const int rg = t >> 4;                           // row group: rows 4rg..4rg+3
  const int x4 = cg << 2;
  const int y0 = rg << 2;

  // Valid tap window in output-grid coords (conv zero-pad + displacement).
  const int xlo = ox > 0 ? ox : 0;
  const int xhi = ox < 0 ? WW + ox : WW;
  const int ylo = oy > 0 ? oy : 0;
  const int yhi = oy < 0 ? HH + oy : HH;

  // Six tap columns xt = x4-1+m (m=0..5); source col = xt-ox = q+m.
  const int q = x4 - 1 - ox;
  float vm[6];
#pragma unroll
  for (int m = 0; m < 6; ++m) {
    const int xt = x4 - 1 + m;
    vm[m] = (xt >= xlo && xt < xhi) ? 1.f : 0.f;
  }

  const float* __restrict__ pbase = inp + (size_t)plane * (HH * WW);
  float* __restrict__ obase = out + (size_t)plane * (HH * WW);
  const float* const lo = inp;
  const float* const hi = inp + (NELEM - 8);

  // Horizontal pass producing one tmp row (4 cols) for tap row ty.
  auto hrow = [&](int ty) -> float4 {
    const float rs = (ty >= ylo && ty < yhi) ? 1.f : 0.f;
    int tsrc = ty - oy;
    tsrc = tsrc < 0 ? 0 : (tsrc > HH - 1 ? HH - 1 : tsrc);
    const float* p = pbase + tsrc * WW + q;
    // Safety clamp into the buffer; never triggers for this input's offsets
    // (extreme |o|=32 positions live at non-extreme plane indices).
    p = p < lo ? lo : (p > hi ? hi : p);
    float s[8];
    __builtin_memcpy(&s[0], p, 16);                // align-4 dwordx4 loads
    __builtin_memcpy(&s[4], p + 4, 16);
#pragma unroll
    for (int m = 0; m < 6; ++m) s[m] *= vm[m];     // fold column masks in
    float4 r;
    r.x = rs * (gx0 * s[0] + gx1 * s[1] + gx2 * s[2]);
    r.y = rs * (gx0 * s[1] + gx1 * s[2] + gx2 * s[3]);
    r.z = rs * (gx0 * s[2] + gx1 * s[3] + gx2 * s[4]);
    r.w = rs * (gx0 * s[3] + gx1 * s[4] + gx2 * s[5]);
    return r;
  };

  // Vertical 3-tap sliding window over 6 tmp rows -> 4 output rows.
  float4 a = hrow(y0 - 1);
  float4 b = hrow(y0);
#pragma unroll
  for (int i = 0; i < 4; ++i) {
    const float4 cc = hrow(y0 + 1 + i);
    float4 o;
    o.x = gy0 * a.x + gy1 * b.x + gy2 * cc.x;
    o.y = gy0 * a.y + gy1 * b.y + gy2 * cc.y;
    o.z = gy0 * a.z + gy1 * b.z + gy2 * cc.z;
    o.w = gy0 * a.w + gy1 * b.w + gy2 * cc.w;
    *(float4*)(obase + (y0 + i) * WW + x4) = o;    // aligned 16B store
    a = b;
    b = cc;
  }
}

extern "C" void kernel_launch(void* const* d_in, const int* in_sizes, int n_in,
                              void* d_out, int out_size, void* d_ws, size_t ws_size,
                              hipStream_t stream) {
  const float* inp = (const float*)d_in[0];
  const float* offset = (const float*)d_in[1];
  float* out = (float*)d_out;
  displace_conv_v2<<<PLANES, 256, 0, stream>>>(inp, offset, out);
}